// Round 13
// baseline (3067.958 us; speedup 1.0000x reference)
//
#include <hip/hip_runtime.h>
#include <hip/hip_bf16.h>
#include <cstdint>
#include <cstddef>

using bf16 = __hip_bfloat16;
typedef short bf16x8 __attribute__((ext_vector_type(8)));
typedef float f32x4 __attribute__((ext_vector_type(4)));

#define CHUNK 64  // FNN_out batching (all 64 steps -> one pass)

__device__ __forceinline__ float fsigmoid(float x) {
  return 1.0f / (1.0f + __expf(-x));
}
__device__ __forceinline__ float ftanh_(float x) {
  float e = __expf(-2.0f * fabsf(x));
  float t = (1.0f - e) / (1.0f + e);
  return copysignf(t, x);
}

__device__ __forceinline__ void gload_lds16(const void* g, void* l) {
  __builtin_amdgcn_global_load_lds(
      (const __attribute__((address_space(1))) void*)g,
      (__attribute__((address_space(3))) void*)l, 16, 0, 0);
}

__global__ void cvt_bf16_kernel(const float* __restrict__ in, bf16* __restrict__ out, int n) {
  int i = blockIdx.x * blockDim.x + threadIdx.x;
  int stride = gridDim.x * blockDim.x;
  for (; i < n; i += stride) out[i] = __float2bfloat16(in[i]);
}

// Build fused gate-blocked weight W'[l][r][k], r = u*64 + gate*16 + v  (unit j = u*16+v)
__global__ void build_wf_kernel(const float* __restrict__ Wih, const float* __restrict__ Whh,
                                const float* __restrict__ bih, const float* __restrict__ bhh,
                                bf16* __restrict__ Wf, float* __restrict__ bfused) {
  int i = blockIdx.x * 256 + threadIdx.x;  // < 3*2048*1024 = 6291456
  int k = i & 1023;
  int r = (i >> 10) & 2047;
  int l = i >> 21;
  int u = r >> 6, gate = (r >> 4) & 3, v = r & 15;
  int j = u * 16 + v;
  int srow = l * 2048 + gate * 512 + j;
  float val = (k < 512) ? Wih[(size_t)srow * 512 + k] : Whh[(size_t)srow * 512 + (k - 512)];
  Wf[i] = __float2bfloat16(val);
  if (k == 0) bfused[l * 2048 + r] = bih[srow] + bhh[srow];
}

// ---------------- shared epilogue ----------------
template <int EPI>
__device__ __forceinline__ void epilogue(
    f32x4 (&acc)[2][4], int m0, int n0, int wr, int wc, int lane,
    const float* __restrict__ bias, void* out0, void* out1, void* out2,
    float* __restrict__ cst, int ldo, int aux, const float (&cpre)[2][4]) {
  const int l16 = lane & 15;
  const int rbase = (lane >> 4) * 4;  // C/D: col = lane&15, row = (lane>>4)*4 + reg

  if constexpr (EPI == 0) {
    bf16* O = (bf16*)out0;
#pragma unroll
    for (int mi = 0; mi < 2; ++mi)
#pragma unroll
      for (int ni = 0; ni < 4; ++ni) {
        int col = n0 + wc * 64 + ni * 16 + l16;
        float bvv = bias[col];
#pragma unroll
        for (int r = 0; r < 4; ++r) {
          int row = m0 + wr * 32 + mi * 16 + rbase + r;
          float v2 = acc[mi][ni][r] + bvv;
          O[(size_t)row * ldo + col] = __float2bfloat16(fmaxf(v2, 0.f));
        }
      }
  } else if constexpr (EPI == 2) {
#pragma unroll
    for (int mi = 0; mi < 2; ++mi)
#pragma unroll
      for (int ni = 0; ni < 4; ++ni) {
        int col = n0 + wc * 64 + ni * 16 + l16;
        int lyr = col >> 9;
        bf16* O = (bf16*)(lyr == 0 ? out0 : (lyr == 1 ? out1 : out2));
        int j = col & 511;
        float bvv = bias[col];
#pragma unroll
        for (int r = 0; r < 4; ++r) {
          int row = m0 + wr * 32 + mi * 16 + rbase + r;
          O[(size_t)row * 512 + j] = __float2bfloat16(acc[mi][ni][r] + bvv);
        }
      }
  } else if constexpr (EPI == 3) {
    bf16* H = (bf16*)out0;
    bf16* Y = (bf16*)out1;
    int ucol = ((n0 >> 6) + wc) * 16 + l16;  // hidden unit index 0..511
    float bi = bias[n0 + wc * 64 + 0 + l16];
    float bff = bias[n0 + wc * 64 + 16 + l16];
    float bg = bias[n0 + wc * 64 + 32 + l16];
    float bo = bias[n0 + wc * 64 + 48 + l16];
#pragma unroll
    for (int mi = 0; mi < 2; ++mi)
#pragma unroll
      for (int r = 0; r < 4; ++r) {
        int row = m0 + wr * 32 + mi * 16 + rbase + r;
        float gi = acc[mi][0][r] + bi;
        float gf = acc[mi][1][r] + bff;
        float gg = acc[mi][2][r] + bg;
        float go = acc[mi][3][r] + bo;
        size_t idx = (size_t)row * 512 + ucol;
        float cold = cpre[mi][r];  // prefetched before the K-loop
        float cn = fsigmoid(gf) * cold + fsigmoid(gi) * ftanh_(gg);
        float hn = fsigmoid(go) * ftanh_(cn);
        cst[idx] = cn;
        bf16 hb = __float2bfloat16(hn);
        H[idx] = hb;
        if (Y) Y[((size_t)row * CHUNK + aux) * 512 + ucol] = hb;
      }
  } else if constexpr (EPI == 4) {
    float* O = (float*)out0;
#pragma unroll
    for (int mi = 0; mi < 2; ++mi)
#pragma unroll
      for (int ni = 0; ni < 4; ++ni) {
        int col = n0 + wc * 64 + ni * 16 + l16;
        float bvv = bias[col];
#pragma unroll
        for (int r = 0; r < 4; ++r) {
          int row = m0 + wr * 32 + mi * 16 + rbase + r;
          int orow = ((row / CHUNK) << 6) + aux + (row % CHUNK);
          O[(size_t)orow * ldo + col] = acc[mi][ni][r] + bvv;
        }
      }
  }
}

// ---------------- LSTM/main GEMM (frozen structure; + cst prefetch for EPI=3) ----------------
// 128x128 tile, BK=64, 8 waves (4x2), 4-deep LDS pipeline (128 KB), lookahead 2,
// one s_barrier per K-step, 2-phase compute with setprio, vmcnt(4).
// EPI=3: the 8 cst loads are issued BEFORE staging; being oldest, every later
// vmcnt(N) over-drains them (correct), and they land under the K-loop.
template <int EPI>
__global__ __launch_bounds__(512) void gemm_bt(
    const bf16* __restrict__ A0, const bf16* __restrict__ A1,
    const bf16* __restrict__ Bw, const float* __restrict__ bias,
    void* __restrict__ out0, void* __restrict__ out1, void* __restrict__ out2,
    float* __restrict__ cst,
    int K, int lda, int ldo, int aux) {
  const int tid = threadIdx.x;
  const int wave = tid >> 6;
  const int lane = tid & 63;

  const int gx = gridDim.x;
  const int nwg = gx * gridDim.y;
  const int flat = blockIdx.x + gx * blockIdx.y;
  int m0, n0;
  if (gx == 16 && gridDim.y == 16) {
    const int xcd = flat & 7;
    const int w = flat >> 3;  // 0..31
    const int mt = (xcd >> 2) * 8 + (w & 7);
    const int nt = (xcd & 3) * 4 + (w >> 3);
    m0 = mt * 128;
    n0 = nt * 128;
  } else {
    const int v = (flat & 7) * (nwg >> 3) + (flat >> 3);
    m0 = (v % gx) * 128;
    n0 = (v / gx) * 128;
  }

  const int wr = wave >> 1, wc = wave & 1;

  __shared__ alignas(16) short ls[4 * 16384];
  char* lsb = (char*)ls;

  f32x4 acc[2][4];
#pragma unroll
  for (int i = 0; i < 2; ++i)
#pragma unroll
    for (int j = 0; j < 4; ++j) acc[i][j] = (f32x4){0.f, 0.f, 0.f, 0.f};

  const int s_row = tid >> 3;
  const int s_k = (((tid & 7) ^ ((tid >> 3) & 7)) * 8);
  const int l16 = lane & 15;
  const int khi = lane >> 4;
  const int sx = l16 & 7;

  const int nk = K >> 6;

  // EPI=3: prefetch old cell state (8 scalar loads) before any staging.
  float cpre[2][4];
  if constexpr (EPI == 3) {
    const int rb = (lane >> 4) * 4;
    int ucol = ((n0 >> 6) + wc) * 16 + l16;
#pragma unroll
    for (int mi = 0; mi < 2; ++mi)
#pragma unroll
      for (int r = 0; r < 4; ++r)
        cpre[mi][r] = cst[(size_t)(m0 + wr * 32 + mi * 16 + rb + r) * 512 + ucol];
  } else {
#pragma unroll
    for (int mi = 0; mi < 2; ++mi)
#pragma unroll
      for (int r = 0; r < 4; ++r) cpre[mi][r] = 0.f;
  }

  auto stage_half = [&](int step, int half) {
    int b = step & 3;
    int kt = step << 6;
    char* base = lsb + b * 32768;
    if (half == 0) {
      const bf16* as = A0;
      int kk = kt;
      if (kt >= 512) { as = A1; kk = kt - 512; }
      gload_lds16(as + (size_t)(m0 + s_row) * lda + kk + s_k, base + tid * 16);
      gload_lds16(as + (size_t)(m0 + 64 + s_row) * lda + kk + s_k, base + 8192 + tid * 16);
    } else {
      gload_lds16(Bw + (size_t)(n0 + s_row) * K + kt + s_k, base + 16384 + tid * 16);
      gload_lds16(Bw + (size_t)(n0 + 64 + s_row) * K + kt + s_k, base + 24576 + tid * 16);
    }
  };

  auto compute_half = [&](int step, int kk) {
    int b = step & 3;
    const short* LA = ls + b * 16384;
    const short* LB = LA + 8192;
    bf16x8 af[2], bv[4];
    int pgA = ((kk * 4 + khi) ^ sx) * 8;
#pragma unroll
    for (int i = 0; i < 2; ++i)
      af[i] = *(const bf16x8*)&LA[(wr * 32 + i * 16 + l16) * 64 + pgA];
#pragma unroll
    for (int i = 0; i < 4; ++i)
      bv[i] = *(const bf16x8*)&LB[(wc * 64 + i * 16 + l16) * 64 + pgA];
    __builtin_amdgcn_s_setprio(1);
#pragma unroll
    for (int mi = 0; mi < 2; ++mi)
#pragma unroll
      for (int ni = 0; ni < 4; ++ni)
        acc[mi][ni] = __builtin_amdgcn_mfma_f32_16x16x32_bf16(af[mi], bv[ni], acc[mi][ni], 0, 0, 0);
    __builtin_amdgcn_s_setprio(0);
  };

  stage_half(0, 0); stage_half(0, 1);
  stage_half(1, 0); stage_half(1, 1);
  for (int t = 0; t < nk - 2; ++t) {
    asm volatile("s_waitcnt vmcnt(4)" ::: "memory");
    __builtin_amdgcn_s_barrier();
    __builtin_amdgcn_sched_barrier(0);
    compute_half(t, 0);
    stage_half(t + 2, 0);
    compute_half(t, 1);
    stage_half(t + 2, 1);
  }
  asm volatile("s_waitcnt vmcnt(4)" ::: "memory");
  __builtin_amdgcn_s_barrier();
  __builtin_amdgcn_sched_barrier(0);
  compute_half(nk - 2, 0);
  compute_half(nk - 2, 1);
  asm volatile("s_waitcnt vmcnt(0)" ::: "memory");
  __builtin_amdgcn_s_barrier();
  __builtin_amdgcn_sched_barrier(0);
  compute_half(nk - 1, 0);
  compute_half(nk - 1, 1);

  epilogue<EPI>(acc, m0, n0, wr, wc, lane, bias, out0, out1, out2, cst, ldo, aux, cpre);
}

// ---------------- high-occupancy GEMM for big FNN passes ----------------
// 2-buffer x 32 KB = 64 KB LDS -> 2 blocks/CU.
// m-clustered XCD map: the nY n-tiles of one m-tile run back-to-back on the SAME
// XCD, so the A (ysc/Z) tile is fetched once into that XCD's L2 and reused.
template <int EPI>
__global__ __launch_bounds__(512) void gemm2(
    const bf16* __restrict__ A0,
    const bf16* __restrict__ Bw, const float* __restrict__ bias,
    void* __restrict__ out0, float* __restrict__ cst,
    int K, int lda, int ldo, int aux) {
  const int tid = threadIdx.x;
  const int wave = tid >> 6;
  const int lane = tid & 63;

  const int gx = gridDim.x;     // m-tiles (multiple of 8)
  const int nY = gridDim.y;     // n-tiles
  const int flat = blockIdx.x + gx * blockIdx.y;
  const int xcd = flat & 7;
  const int seq = flat >> 3;    // 0 .. gx*nY/8-1
  const int mpx = gx >> 3;      // m-tiles per XCD
  const int m0 = (xcd * mpx + seq / nY) * 128;
  const int n0 = (seq % nY) * 128;

  const int wr = wave >> 1, wc = wave & 1;

  __shared__ alignas(16) short ls[2 * 16384];
  char* lsb = (char*)ls;

  f32x4 acc[2][4];
#pragma unroll
  for (int i = 0; i < 2; ++i)
#pragma unroll
    for (int j = 0; j < 4; ++j) acc[i][j] = (f32x4){0.f, 0.f, 0.f, 0.f};

  const int s_row = tid >> 3;
  const int s_k = (((tid & 7) ^ ((tid >> 3) & 7)) * 8);
  const int l16 = lane & 15;
  const int khi = lane >> 4;
  const int sx = l16 & 7;

  const int nk = K >> 6;

  auto stage = [&](int step) {
    int b = step & 1;
    int kt = step << 6;
    char* base = lsb + b * 32768;
    gload_lds16(A0 + (size_t)(m0 + s_row) * lda + kt + s_k, base + tid * 16);
    gload_lds16(A0 + (size_t)(m0 + 64 + s_row) * lda + kt + s_k, base + 8192 + tid * 16);
    gload_lds16(Bw + (size_t)(n0 + s_row) * K + kt + s_k, base + 16384 + tid * 16);
    gload_lds16(Bw + (size_t)(n0 + 64 + s_row) * K + kt + s_k, base + 24576 + tid * 16);
  };

  auto compute = [&](int step) {
    int b = step & 1;
    const short* LA = ls + b * 16384;
    const short* LB = LA + 8192;
    bf16x8 af[2][2], bv[4][2];
#pragma unroll
    for (int kk = 0; kk < 2; ++kk) {
      int pgA = ((kk * 4 + khi) ^ sx) * 8;
#pragma unroll
      for (int i = 0; i < 2; ++i)
        af[i][kk] = *(const bf16x8*)&LA[(wr * 32 + i * 16 + l16) * 64 + pgA];
#pragma unroll
      for (int i = 0; i < 4; ++i)
        bv[i][kk] = *(const bf16x8*)&LB[(wc * 64 + i * 16 + l16) * 64 + pgA];
    }
    __builtin_amdgcn_s_setprio(1);
#pragma unroll
    for (int kk = 0; kk < 2; ++kk)
#pragma unroll
      for (int mi = 0; mi < 2; ++mi)
#pragma unroll
        for (int ni = 0; ni < 4; ++ni)
          acc[mi][ni] = __builtin_amdgcn_mfma_f32_16x16x32_bf16(af[mi][kk], bv[ni][kk], acc[mi][ni], 0, 0, 0);
    __builtin_amdgcn_s_setprio(0);
  };

  stage(0);
  for (int t = 0; t < nk; ++t) {
    asm volatile("s_waitcnt vmcnt(0)" ::: "memory");
    __builtin_amdgcn_s_barrier();
    __builtin_amdgcn_sched_barrier(0);
    if (t + 1 < nk) stage(t + 1);
    compute(t);
  }

  float cdum[2][4] = {};
  epilogue<EPI>(acc, m0, n0, wr, wc, lane, bias, out0, nullptr, nullptr, cst, ldo, aux, cdum);
}

extern "C" void kernel_launch(void* const* d_in, const int* in_sizes, int n_in,
                              void* d_out, int out_size, void* d_ws, size_t ws_size,
                              hipStream_t stream) {
  const float* emb = (const float*)d_in[0];
  const float* Win1 = (const float*)d_in[1];
  const float* bin1 = (const float*)d_in[2];
  const float* Win2 = (const float*)d_in[3];
  const float* bin2 = (const float*)d_in[4];
  const float* Wih = (const float*)d_in[5];
  const float* Whh = (const float*)d_in[6];
  const float* bih = (const float*)d_in[7];
  const float* bhh = (const float*)d_in[8];
  const float* Wout1 = (const float*)d_in[9];
  const float* bout1 = (const float*)d_in[10];
  const float* Wout2 = (const float*)d_in[11];
  const float* bout2 = (const float*)d_in[12];
  float* out = (float*)d_out;
  (void)in_sizes; (void)n_in; (void)out_size; (void)ws_size;

  char* p = (char*)d_ws;
  auto carve = [&](size_t bytes) {
    char* r = p;
    p += (bytes + 255) & ~(size_t)255;
    return r;
  };

  bf16* Wf = (bf16*)carve((size_t)3 * 2048 * 1024 * 2);
  float* bfuse = (float*)carve((size_t)3 * 2048 * 4);
  bf16* Win1b = (bf16*)carve((size_t)512 * 512 * 2);
  bf16* Win2b = (bf16*)carve((size_t)1536 * 512 * 2);
  bf16* Wout1b = (bf16*)carve((size_t)512 * 512 * 2);
  bf16* Wout2b = (bf16*)carve((size_t)256 * 512 * 2);
  bf16* embb = (bf16*)carve((size_t)2048 * 512 * 2);
  bf16* C1 = (bf16*)carve((size_t)2048 * 512 * 2);
  bf16* hbuf = (bf16*)carve((size_t)2 * 3 * 2048 * 512 * 2);  // [set][layer][2048][512]
  float* cst = (float*)carve((size_t)3 * 2048 * 512 * 4);
  bf16* x0 = (bf16*)carve((size_t)2048 * 512 * 2);
  bf16* ysc = (bf16*)carve((size_t)2048 * CHUNK * 512 * 2);   // rows ordered b*CHUNK+tc
  bf16* Z = (bf16*)carve((size_t)2048 * CHUNK * 512 * 2);

  hipMemsetAsync(cst, 0, (size_t)3 * 2048 * 512 * 4, stream);
  hipMemsetAsync(x0, 0, (size_t)2048 * 512 * 2, stream);

  cvt_bf16_kernel<<<1024, 256, 0, stream>>>(emb, embb, 2048 * 512);
  cvt_bf16_kernel<<<1024, 256, 0, stream>>>(Win1, Win1b, 512 * 512);
  cvt_bf16_kernel<<<1024, 256, 0, stream>>>(Win2, Win2b, 1536 * 512);
  cvt_bf16_kernel<<<1024, 256, 0, stream>>>(Wout1, Wout1b, 512 * 512);
  cvt_bf16_kernel<<<512, 256, 0, stream>>>(Wout2, Wout2b, 256 * 512);
  build_wf_kernel<<<(3 * 2048 * 1024) / 256, 256, 0, stream>>>(Wih, Whh, bih, bhh, Wf, bfuse);

  auto hset = [&](int s, int l) { return hbuf + ((size_t)s * 3 + l) * 2048 * 512; };

  // FNN_in: C1 = relu(emb @ Win1^T + bin1); h_init = C1 @ Win2^T + bin2 (split into 3 layers)
  gemm_bt<0><<<dim3(16, 4), 512, 0, stream>>>(embb, nullptr, Win1b, bin1,
                                              C1, nullptr, nullptr, nullptr, 512, 512, 512, 0);
  gemm_bt<2><<<dim3(16, 12), 512, 0, stream>>>(C1, nullptr, Win2b, bin2,
                                               hset(0, 0), hset(0, 1), hset(0, 2), nullptr,
                                               512, 512, 0, 0);

  for (int t = 0; t < 64; ++t) {
    int cur = t & 1;
    bf16* hR0 = hset(cur, 0);
    bf16* hR1 = hset(cur, 1);
    bf16* hR2 = hset(cur, 2);
    bf16* hW0 = hset(cur ^ 1, 0);
    bf16* hW1 = hset(cur ^ 1, 1);
    bf16* hW2 = hset(cur ^ 1, 2);
    const bf16* inp0 = (t == 0) ? (const bf16*)x0 : (const bf16*)hR2;
    int tc = t % CHUNK;

    gemm_bt<3><<<dim3(16, 16), 512, 0, stream>>>(inp0, hR0, Wf, bfuse,
                                                 hW0, nullptr, nullptr, cst,
                                                 1024, 512, 0, tc);
    gemm_bt<3><<<dim3(16, 16), 512, 0, stream>>>(hW0, hR1, Wf + (size_t)2048 * 1024, bfuse + 2048,
                                                 hW1, nullptr, nullptr, cst + (size_t)2048 * 512,
                                                 1024, 512, 0, tc);
    gemm_bt<3><<<dim3(16, 16), 512, 0, stream>>>(hW1, hR2, Wf + (size_t)2 * 2048 * 1024, bfuse + 2 * 2048,
                                                 hW2, ysc, nullptr, cst + (size_t)2 * 2048 * 512,
                                                 1024, 512, 0, tc);

    if (tc == CHUNK - 1) {
      // FNN_out on the CHUNK-step batch: M = 2048*CHUNK
      gemm2<0><<<dim3(2048 * CHUNK / 128, 4), 512, 0, stream>>>(
          ysc, Wout1b, bout1, Z, nullptr, 512, 512, 512, 0);
      gemm2<4><<<dim3(2048 * CHUNK / 128, 2), 512, 0, stream>>>(
          Z, Wout2b, bout2, out, nullptr, 512, 512, 256, t - (CHUNK - 1));
    }
  }
}

// Round 14
// 2984.602 us; speedup vs baseline: 1.0279x; 1.0279x over previous
//
#include <hip/hip_runtime.h>
#include <hip/hip_bf16.h>
#include <cstdint>
#include <cstddef>

using bf16 = __hip_bfloat16;
typedef short bf16x8 __attribute__((ext_vector_type(8)));
typedef float f32x4 __attribute__((ext_vector_type(4)));

#define CHUNK 64  // FNN_out batching (all 64 steps -> one pass)

__device__ __forceinline__ float fsigmoid(float x) {
  return 1.0f / (1.0f + __expf(-x));
}
__device__ __forceinline__ float ftanh_(float x) {
  float e = __expf(-2.0f * fabsf(x));
  float t = (1.0f - e) / (1.0f + e);
  return copysignf(t, x);
}

__device__ __forceinline__ void gload_lds16(const void* g, void* l) {
  __builtin_amdgcn_global_load_lds(
      (const __attribute__((address_space(1))) void*)g,
      (__attribute__((address_space(3))) void*)l, 16, 0, 0);
}

__global__ void cvt_bf16_kernel(const float* __restrict__ in, bf16* __restrict__ out, int n) {
  int i = blockIdx.x * blockDim.x + threadIdx.x;
  int stride = gridDim.x * blockDim.x;
  for (; i < n; i += stride) out[i] = __float2bfloat16(in[i]);
}

// Build fused gate-blocked weight W'[l][r][k], r = u*64 + gate*16 + v  (unit j = u*16+v)
__global__ void build_wf_kernel(const float* __restrict__ Wih, const float* __restrict__ Whh,
                                const float* __restrict__ bih, const float* __restrict__ bhh,
                                bf16* __restrict__ Wf, float* __restrict__ bfused) {
  int i = blockIdx.x * 256 + threadIdx.x;  // < 3*2048*1024 = 6291456
  int k = i & 1023;
  int r = (i >> 10) & 2047;
  int l = i >> 21;
  int u = r >> 6, gate = (r >> 4) & 3, v = r & 15;
  int j = u * 16 + v;
  int srow = l * 2048 + gate * 512 + j;
  float val = (k < 512) ? Wih[(size_t)srow * 512 + k] : Whh[(size_t)srow * 512 + (k - 512)];
  Wf[i] = __float2bfloat16(val);
  if (k == 0) bfused[l * 2048 + r] = bih[srow] + bhh[srow];
}

// ---------------- shared epilogue (R11 version — cst read in-place) ----------------
template <int EPI>
__device__ __forceinline__ void epilogue(
    f32x4 (&acc)[2][4], int m0, int n0, int wr, int wc, int lane,
    const float* __restrict__ bias, void* out0, void* out1, void* out2,
    float* __restrict__ cst, int ldo, int aux) {
  const int l16 = lane & 15;
  const int rbase = (lane >> 4) * 4;  // C/D: col = lane&15, row = (lane>>4)*4 + reg

  if constexpr (EPI == 0) {
    bf16* O = (bf16*)out0;
#pragma unroll
    for (int mi = 0; mi < 2; ++mi)
#pragma unroll
      for (int ni = 0; ni < 4; ++ni) {
        int col = n0 + wc * 64 + ni * 16 + l16;
        float bvv = bias[col];
#pragma unroll
        for (int r = 0; r < 4; ++r) {
          int row = m0 + wr * 32 + mi * 16 + rbase + r;
          float v2 = acc[mi][ni][r] + bvv;
          O[(size_t)row * ldo + col] = __float2bfloat16(fmaxf(v2, 0.f));
        }
      }
  } else if constexpr (EPI == 2) {
#pragma unroll
    for (int mi = 0; mi < 2; ++mi)
#pragma unroll
      for (int ni = 0; ni < 4; ++ni) {
        int col = n0 + wc * 64 + ni * 16 + l16;
        int lyr = col >> 9;
        bf16* O = (bf16*)(lyr == 0 ? out0 : (lyr == 1 ? out1 : out2));
        int j = col & 511;
        float bvv = bias[col];
#pragma unroll
        for (int r = 0; r < 4; ++r) {
          int row = m0 + wr * 32 + mi * 16 + rbase + r;
          O[(size_t)row * 512 + j] = __float2bfloat16(acc[mi][ni][r] + bvv);
        }
      }
  } else if constexpr (EPI == 3) {
    bf16* H = (bf16*)out0;
    bf16* Y = (bf16*)out1;
    int ucol = ((n0 >> 6) + wc) * 16 + l16;  // hidden unit index 0..511
    float bi = bias[n0 + wc * 64 + 0 + l16];
    float bff = bias[n0 + wc * 64 + 16 + l16];
    float bg = bias[n0 + wc * 64 + 32 + l16];
    float bo = bias[n0 + wc * 64 + 48 + l16];
#pragma unroll
    for (int mi = 0; mi < 2; ++mi)
#pragma unroll
      for (int r = 0; r < 4; ++r) {
        int row = m0 + wr * 32 + mi * 16 + rbase + r;
        float gi = acc[mi][0][r] + bi;
        float gf = acc[mi][1][r] + bff;
        float gg = acc[mi][2][r] + bg;
        float go = acc[mi][3][r] + bo;
        size_t idx = (size_t)row * 512 + ucol;
        float cold = cst[idx];
        float cn = fsigmoid(gf) * cold + fsigmoid(gi) * ftanh_(gg);
        float hn = fsigmoid(go) * ftanh_(cn);
        cst[idx] = cn;
        bf16 hb = __float2bfloat16(hn);
        H[idx] = hb;
        if (Y) Y[((size_t)row * CHUNK + aux) * 512 + ucol] = hb;
      }
  } else if constexpr (EPI == 4) {
    float* O = (float*)out0;
#pragma unroll
    for (int mi = 0; mi < 2; ++mi)
#pragma unroll
      for (int ni = 0; ni < 4; ++ni) {
        int col = n0 + wc * 64 + ni * 16 + l16;
        float bvv = bias[col];
#pragma unroll
        for (int r = 0; r < 4; ++r) {
          int row = m0 + wr * 32 + mi * 16 + rbase + r;
          int orow = ((row / CHUNK) << 6) + aux + (row % CHUNK);
          O[(size_t)orow * ldo + col] = acc[mi][ni][r] + bvv;
        }
      }
  }
}

// ---------------- LSTM/main GEMM (FROZEN — R11 best) ----------------
// 128x128 tile, BK=64, 8 waves (4x2), 4-deep LDS pipeline (128 KB), lookahead 2,
// one s_barrier per K-step, 2-phase compute with setprio, vmcnt(4).
template <int EPI>
__global__ __launch_bounds__(512) void gemm_bt(
    const bf16* __restrict__ A0, const bf16* __restrict__ A1,
    const bf16* __restrict__ Bw, const float* __restrict__ bias,
    void* __restrict__ out0, void* __restrict__ out1, void* __restrict__ out2,
    float* __restrict__ cst,
    int K, int lda, int ldo, int aux) {
  const int tid = threadIdx.x;
  const int wave = tid >> 6;
  const int lane = tid & 63;

  const int gx = gridDim.x;
  const int nwg = gx * gridDim.y;
  const int flat = blockIdx.x + gx * blockIdx.y;
  int m0, n0;
  if (gx == 16 && gridDim.y == 16) {
    const int xcd = flat & 7;
    const int w = flat >> 3;  // 0..31
    const int mt = (xcd >> 2) * 8 + (w & 7);
    const int nt = (xcd & 3) * 4 + (w >> 3);
    m0 = mt * 128;
    n0 = nt * 128;
  } else {
    const int v = (flat & 7) * (nwg >> 3) + (flat >> 3);
    m0 = (v % gx) * 128;
    n0 = (v / gx) * 128;
  }

  const int wr = wave >> 1, wc = wave & 1;

  __shared__ alignas(16) short ls[4 * 16384];
  char* lsb = (char*)ls;

  f32x4 acc[2][4];
#pragma unroll
  for (int i = 0; i < 2; ++i)
#pragma unroll
    for (int j = 0; j < 4; ++j) acc[i][j] = (f32x4){0.f, 0.f, 0.f, 0.f};

  const int s_row = tid >> 3;
  const int s_k = (((tid & 7) ^ ((tid >> 3) & 7)) * 8);
  const int l16 = lane & 15;
  const int khi = lane >> 4;
  const int sx = l16 & 7;

  const int nk = K >> 6;

  auto stage_half = [&](int step, int half) {
    int b = step & 3;
    int kt = step << 6;
    char* base = lsb + b * 32768;
    if (half == 0) {
      const bf16* as = A0;
      int kk = kt;
      if (kt >= 512) { as = A1; kk = kt - 512; }
      gload_lds16(as + (size_t)(m0 + s_row) * lda + kk + s_k, base + tid * 16);
      gload_lds16(as + (size_t)(m0 + 64 + s_row) * lda + kk + s_k, base + 8192 + tid * 16);
    } else {
      gload_lds16(Bw + (size_t)(n0 + s_row) * K + kt + s_k, base + 16384 + tid * 16);
      gload_lds16(Bw + (size_t)(n0 + 64 + s_row) * K + kt + s_k, base + 24576 + tid * 16);
    }
  };

  auto compute_half = [&](int step, int kk) {
    int b = step & 3;
    const short* LA = ls + b * 16384;
    const short* LB = LA + 8192;
    bf16x8 af[2], bv[4];
    int pgA = ((kk * 4 + khi) ^ sx) * 8;
#pragma unroll
    for (int i = 0; i < 2; ++i)
      af[i] = *(const bf16x8*)&LA[(wr * 32 + i * 16 + l16) * 64 + pgA];
#pragma unroll
    for (int i = 0; i < 4; ++i)
      bv[i] = *(const bf16x8*)&LB[(wc * 64 + i * 16 + l16) * 64 + pgA];
    __builtin_amdgcn_s_setprio(1);
#pragma unroll
    for (int mi = 0; mi < 2; ++mi)
#pragma unroll
      for (int ni = 0; ni < 4; ++ni)
        acc[mi][ni] = __builtin_amdgcn_mfma_f32_16x16x32_bf16(af[mi], bv[ni], acc[mi][ni], 0, 0, 0);
    __builtin_amdgcn_s_setprio(0);
  };

  stage_half(0, 0); stage_half(0, 1);
  stage_half(1, 0); stage_half(1, 1);
  for (int t = 0; t < nk - 2; ++t) {
    asm volatile("s_waitcnt vmcnt(4)" ::: "memory");
    __builtin_amdgcn_s_barrier();
    __builtin_amdgcn_sched_barrier(0);
    compute_half(t, 0);
    stage_half(t + 2, 0);
    compute_half(t, 1);
    stage_half(t + 2, 1);
  }
  asm volatile("s_waitcnt vmcnt(4)" ::: "memory");
  __builtin_amdgcn_s_barrier();
  __builtin_amdgcn_sched_barrier(0);
  compute_half(nk - 2, 0);
  compute_half(nk - 2, 1);
  asm volatile("s_waitcnt vmcnt(0)" ::: "memory");
  __builtin_amdgcn_s_barrier();
  __builtin_amdgcn_sched_barrier(0);
  compute_half(nk - 1, 0);
  compute_half(nk - 1, 1);

  epilogue<EPI>(acc, m0, n0, wr, wc, lane, bias, out0, out1, out2, cst, ldo, aux);
}

// ---------------- high-occupancy pipelined GEMM for big FNN passes ----------------
// BK=32, 4 buffers x 16 KB = 64 KB LDS -> 2 blocks/CU. Lookahead 2, counted
// vmcnt(4) (2 loads/thread/window, 2 windows in flight at the wait), ONE barrier
// per step (4-buffer WAR slack, same argument as the LSTM kernel).
// Swizzle: R5-verified constants — physical granule p = g ^ ((row>>1)&3), 2-way free.
// m-clustered XCD map: the nY n-tiles of one m-tile run back-to-back on one XCD.
template <int EPI>
__global__ __launch_bounds__(512) void gemm2(
    const bf16* __restrict__ A0,
    const bf16* __restrict__ Bw, const float* __restrict__ bias,
    void* __restrict__ out0, float* __restrict__ cst,
    int K, int lda, int ldo, int aux) {
  const int tid = threadIdx.x;
  const int wave = tid >> 6;
  const int lane = tid & 63;

  const int gx = gridDim.x;     // m-tiles (multiple of 8)
  const int nY = gridDim.y;     // n-tiles
  const int flat = blockIdx.x + gx * blockIdx.y;
  const int xcd = flat & 7;
  const int seq = flat >> 3;    // 0 .. gx*nY/8-1
  const int mpx = gx >> 3;      // m-tiles per XCD
  const int m0 = (xcd * mpx + seq / nY) * 128;
  const int n0 = (seq % nY) * 128;

  const int wr = wave >> 1, wc = wave & 1;

  // 4 buffers x (A: 128x32 | B: 128x32 shorts) = 64 KB
  __shared__ alignas(16) short ls[4 * 8192];
  char* lsb = (char*)ls;

  f32x4 acc[2][4];
#pragma unroll
  for (int i = 0; i < 2; ++i)
#pragma unroll
    for (int j = 0; j < 4; ++j) acc[i][j] = (f32x4){0.f, 0.f, 0.f, 0.f};

  const int s_row = tid >> 2;  // 0..127 (each thread stages 16B of one row)
  const int s_k = (((tid & 3) ^ ((tid >> 3) & 3)) * 8);  // inverse-swizzled granule
  const int l16 = lane & 15;
  const int sw = (((lane >> 4) ^ ((l16 >> 1) & 3)) << 3);  // read granule (shorts)

  const int nk = K >> 5;

  auto stage = [&](int step) {
    int b = step & 3;
    int kt = step << 5;
    char* base = lsb + b * 16384;
    gload_lds16(A0 + (size_t)(m0 + s_row) * lda + kt + s_k, base + tid * 16);
    gload_lds16(Bw + (size_t)(n0 + s_row) * K + kt + s_k, base + 8192 + tid * 16);
  };

  auto compute = [&](int step) {
    int b = step & 3;
    const short* LA = ls + b * 8192;
    const short* LB = LA + 4096;
    bf16x8 af[2], bv[4];
#pragma unroll
    for (int i = 0; i < 2; ++i)
      af[i] = *(const bf16x8*)&LA[(wr * 32 + i * 16 + l16) * 32 + sw];
#pragma unroll
    for (int i = 0; i < 4; ++i)
      bv[i] = *(const bf16x8*)&LB[(wc * 64 + i * 16 + l16) * 32 + sw];
    __builtin_amdgcn_s_setprio(1);
#pragma unroll
    for (int mi = 0; mi < 2; ++mi)
#pragma unroll
      for (int ni = 0; ni < 4; ++ni)
        acc[mi][ni] = __builtin_amdgcn_mfma_f32_16x16x32_bf16(af[mi], bv[ni], acc[mi][ni], 0, 0, 0);
    __builtin_amdgcn_s_setprio(0);
  };

  stage(0);
  stage(1);
  for (int t = 0; t < nk - 2; ++t) {
    stage(t + 2);                                     // windows t,t+1,t+2 out (6 loads)
    asm volatile("s_waitcnt vmcnt(4)" ::: "memory");  // window t landed
    __builtin_amdgcn_s_barrier();
    __builtin_amdgcn_sched_barrier(0);
    compute(t);                                       // one barrier/step (4-buf WAR slack)
  }
  asm volatile("s_waitcnt vmcnt(2)" ::: "memory");
  __builtin_amdgcn_s_barrier();
  __builtin_amdgcn_sched_barrier(0);
  compute(nk - 2);
  asm volatile("s_waitcnt vmcnt(0)" ::: "memory");
  __builtin_amdgcn_s_barrier();
  __builtin_amdgcn_sched_barrier(0);
  compute(nk - 1);

  epilogue<EPI>(acc, m0, n0, wr, wc, lane, bias, out0, nullptr, nullptr, cst, ldo, aux);
}

extern "C" void kernel_launch(void* const* d_in, const int* in_sizes, int n_in,
                              void* d_out, int out_size, void* d_ws, size_t ws_size,
                              hipStream_t stream) {
  const float* emb = (const float*)d_in[0];
  const float* Win1 = (const float*)d_in[1];
  const float* bin1 = (const float*)d_in[2];
  const float* Win2 = (const float*)d_in[3];
  const float* bin2 = (const float*)d_in[4];
  const float* Wih = (const float*)d_in[5];
  const float* Whh = (const float*)d_in[6];
  const float* bih = (const float*)d_in[7];
  const float* bhh = (const float*)d_in[8];
  const float* Wout1 = (const float*)d_in[9];
  const float* bout1 = (const float*)d_in[10];
  const float* Wout2 = (const float*)d_in[11];
  const float* bout2 = (const float*)d_in[12];
  float* out = (float*)d_out;
  (void)in_sizes; (void)n_in; (void)out_size; (void)ws_size;

  char* p = (char*)d_ws;
  auto carve = [&](size_t bytes) {
    char* r = p;
    p += (bytes + 255) & ~(size_t)255;
    return r;
  };

  bf16* Wf = (bf16*)carve((size_t)3 * 2048 * 1024 * 2);
  float* bfuse = (float*)carve((size_t)3 * 2048 * 4);
  bf16* Win1b = (bf16*)carve((size_t)512 * 512 * 2);
  bf16* Win2b = (bf16*)carve((size_t)1536 * 512 * 2);
  bf16* Wout1b = (bf16*)carve((size_t)512 * 512 * 2);
  bf16* Wout2b = (bf16*)carve((size_t)256 * 512 * 2);
  bf16* embb = (bf16*)carve((size_t)2048 * 512 * 2);
  bf16* C1 = (bf16*)carve((size_t)2048 * 512 * 2);
  bf16* hbuf = (bf16*)carve((size_t)2 * 3 * 2048 * 512 * 2);  // [set][layer][2048][512]
  float* cst = (float*)carve((size_t)3 * 2048 * 512 * 4);
  bf16* x0 = (bf16*)carve((size_t)2048 * 512 * 2);
  bf16* ysc = (bf16*)carve((size_t)2048 * CHUNK * 512 * 2);   // rows ordered b*CHUNK+tc
  bf16* Z = (bf16*)carve((size_t)2048 * CHUNK * 512 * 2);

  hipMemsetAsync(cst, 0, (size_t)3 * 2048 * 512 * 4, stream);
  hipMemsetAsync(x0, 0, (size_t)2048 * 512 * 2, stream);

  cvt_bf16_kernel<<<1024, 256, 0, stream>>>(emb, embb, 2048 * 512);
  cvt_bf16_kernel<<<1024, 256, 0, stream>>>(Win1, Win1b, 512 * 512);
  cvt_bf16_kernel<<<1024, 256, 0, stream>>>(Win2, Win2b, 1536 * 512);
  cvt_bf16_kernel<<<1024, 256, 0, stream>>>(Wout1, Wout1b, 512 * 512);
  cvt_bf16_kernel<<<512, 256, 0, stream>>>(Wout2, Wout2b, 256 * 512);
  build_wf_kernel<<<(3 * 2048 * 1024) / 256, 256, 0, stream>>>(Wih, Whh, bih, bhh, Wf, bfuse);

  auto hset = [&](int s, int l) { return hbuf + ((size_t)s * 3 + l) * 2048 * 512; };

  // FNN_in: C1 = relu(emb @ Win1^T + bin1); h_init = C1 @ Win2^T + bin2 (split into 3 layers)
  gemm_bt<0><<<dim3(16, 4), 512, 0, stream>>>(embb, nullptr, Win1b, bin1,
                                              C1, nullptr, nullptr, nullptr, 512, 512, 512, 0);
  gemm_bt<2><<<dim3(16, 12), 512, 0, stream>>>(C1, nullptr, Win2b, bin2,
                                               hset(0, 0), hset(0, 1), hset(0, 2), nullptr,
                                               512, 512, 0, 0);

  for (int t = 0; t < 64; ++t) {
    int cur = t & 1;
    bf16* hR0 = hset(cur, 0);
    bf16* hR1 = hset(cur, 1);
    bf16* hR2 = hset(cur, 2);
    bf16* hW0 = hset(cur ^ 1, 0);
    bf16* hW1 = hset(cur ^ 1, 1);
    bf16* hW2 = hset(cur ^ 1, 2);
    const bf16* inp0 = (t == 0) ? (const bf16*)x0 : (const bf16*)hR2;
    int tc = t % CHUNK;

    gemm_bt<3><<<dim3(16, 16), 512, 0, stream>>>(inp0, hR0, Wf, bfuse,
                                                 hW0, nullptr, nullptr, cst,
                                                 1024, 512, 0, tc);
    gemm_bt<3><<<dim3(16, 16), 512, 0, stream>>>(hW0, hR1, Wf + (size_t)2048 * 1024, bfuse + 2048,
                                                 hW1, nullptr, nullptr, cst + (size_t)2048 * 512,
                                                 1024, 512, 0, tc);
    gemm_bt<3><<<dim3(16, 16), 512, 0, stream>>>(hW1, hR2, Wf + (size_t)2 * 2048 * 1024, bfuse + 2 * 2048,
                                                 hW2, ysc, nullptr, cst + (size_t)2 * 2048 * 512,
                                                 1024, 512, 0, tc);

    if (tc == CHUNK - 1) {
      // FNN_out on the CHUNK-step batch: M = 2048*CHUNK
      gemm2<0><<<dim3(2048 * CHUNK / 128, 4), 512, 0, stream>>>(
          ysc, Wout1b, bout1, Z, nullptr, 512, 512, 512, 0);
      gemm2<4><<<dim3(2048 * CHUNK / 128, 2), 512, 0, stream>>>(
          Z, Wout2b, bout2, out, nullptr, 512, 512, 256, t - (CHUNK - 1));
    }
  }
}